// Round 4
// baseline (150.223 us; speedup 1.0000x reference)
//
#include <hip/hip_runtime.h>
#include <stdint.h>

#define B_ 1024
#define N_ 128
#define D_ 128
#define H_ 256
#define L_ 64
#define INF_ 0x3FFFFFFF

// ws byte offsets
#define WS_W1   0u          // W1T A-frags: 32768 u16 = 65536 B
#define WS_W2   65536u      // W2 B-frags: 65536 u16 = 131072 B
#define WS_TREE 196608u     // per-graph 3072 B: tnbr[128][4] u32 | inv[128] f32 | wm[128] f32
#define WS_G    3342336u    // pooled g: [1024][256] f32

typedef __attribute__((ext_vector_type(8))) short bf16x8;
typedef __attribute__((ext_vector_type(4))) float f32x4;
typedef __attribute__((ext_vector_type(4))) uint32_t u32x4;
typedef __attribute__((ext_vector_type(2))) uint32_t u32x2;

__device__ __forceinline__ uint16_t f2b(float f) {
    uint32_t u = __float_as_uint(f);
    return (uint16_t)((u + 0x7FFFu + ((u >> 16) & 1u)) >> 16);   // RNE
}
__device__ __forceinline__ uint32_t pack2(float a, float b) {
    return (uint32_t)f2b(a) | ((uint32_t)f2b(b) << 16);
}

// ---------------- weight prep: fragment-linear bf16 layouts in ws ----------------
__global__ void prep_weights(const float* __restrict__ W1, const float* __restrict__ W2,
                             uint16_t* __restrict__ ws) {
    int t = blockIdx.x * 256 + threadIdx.x;
    if (t < 4096) {                       // W1T A-frags: A[m=h][k=f]
        int lane = t & 63, fkb = t >> 6;
        int tm = fkb >> 2, kb = fkb & 3;
        int h  = tm * 16 + (lane & 15);
        int k0 = kb * 32 + (lane >> 4) * 8;
        u32x4 w;
        #pragma unroll
        for (int p = 0; p < 4; ++p)
            w[p] = pack2(W1[(k0 + 2*p) * H_ + h], W1[(k0 + 2*p + 1) * H_ + h]);
        *reinterpret_cast<u32x4*>(&ws[t * 8]) = w;
    } else if (t < 12288) {               // W2 B-frags: B[k][n]
        int t2 = t - 4096;
        int lane = t2 & 63, g = t2 >> 6;
        int tn = g >> 3, kb = g & 7;
        int n  = tn * 16 + (lane & 15);
        int k0 = kb * 32 + (lane >> 4) * 8;
        u32x4 w;
        #pragma unroll
        for (int p = 0; p < 4; ++p)
            w[p] = pack2(W2[(k0 + 2*p) * H_ + n], W2[(k0 + 2*p + 1) * H_ + n]);
        *reinterpret_cast<u32x4*>(&ws[32768 + t2 * 8]) = w;
    }
}

// ---------------- K1: BFS spanning tree per graph ----------------
__global__ __launch_bounds__(256, 4) void tree_kernel(
    const float* __restrict__ adj, uint8_t* __restrict__ wsb)
{
    __shared__ uint32_t adjm[128][4];
    __shared__ __align__(16) uint32_t tnbr[128][4];
    __shared__ int      s_order[128];
    __shared__ int      s_parent[128];
    __shared__ int      s_key[128];
    __shared__ uint32_t visw[4], actw[4], newlyw[4];
    __shared__ int      s_root;

    const int tid = threadIdx.x;
    const int b   = blockIdx.x;
    const float* ag = adj + (size_t)b * N_ * N_;

    if (tid < 128) { s_order[tid] = INF_; s_parent[tid] = 0; }
    if (tid < 4)   { visw[tid] = 0u; actw[tid] = 0u; }
    if (tid == 0)  { s_root = 128; }
    {
        const int v = tid >> 1, hf = tid & 1;
        const float4* ag4 = reinterpret_cast<const float4*>(ag + v * N_ + hf * 64);
        uint32_t w0 = 0, w1 = 0;
        #pragma unroll
        for (int i = 0; i < 16; ++i) {
            float4 f = ag4[i];
            uint32_t bs = (f.x > 0.5f ? 1u : 0u) | (f.y > 0.5f ? 2u : 0u) |
                          (f.z > 0.5f ? 4u : 0u) | (f.w > 0.5f ? 8u : 0u);
            int base = i * 4;
            if (base < 32) w0 |= bs << base; else w1 |= bs << (base - 32);
        }
        adjm[v][hf * 2]     = w0;
        adjm[v][hf * 2 + 1] = w1;
    }
    __syncthreads();

    if (tid < 128) {
        uint32_t any = adjm[tid][0] | adjm[tid][1] | adjm[tid][2] | adjm[tid][3];
        if (any) {
            atomicMin(&s_root, tid);
            atomicOr(&actw[tid >> 5], 1u << (tid & 31));
        }
    }
    __syncthreads();
    int counter = 0;
    if (s_root < 128) {
        counter = 1;
        if (tid == 0) {
            s_order[s_root] = 0;
            visw[s_root >> 5] = 1u << (s_root & 31);
        }
    }
    __syncthreads();

    for (int step = 0; step < N_ - 1; ++step) {
        if (tid < 4) newlyw[tid] = 0u;
        __syncthreads();
        int newly = 0, po = INF_, par = 0;
        if (tid < 128 && s_order[tid] >= INF_) {
            #pragma unroll
            for (int w = 0; w < 4; ++w) {
                uint32_t m = adjm[tid][w] & visw[w];
                while (m) {
                    int u = (w << 5) + __ffs(m) - 1; m &= m - 1;
                    int o = s_order[u];
                    if (o < po) { po = o; par = u; }
                }
            }
            newly = (po < INF_);
            if (newly) {
                s_key[tid] = po * N_ + tid;
                atomicOr(&newlyw[tid >> 5], 1u << (tid & 31));
            }
        }
        __syncthreads();
        int myk = newly ? po * N_ + tid : 0x7FFFFFFF;
        int cnt = 0, rank = 0;
        #pragma unroll
        for (int w = 0; w < 4; ++w) {
            uint32_t m = newlyw[w];
            cnt += __popc(m);
            while (m) {
                int u = (w << 5) + __ffs(m) - 1; m &= m - 1;
                rank += (s_key[u] < myk);
            }
        }
        if (newly) {
            s_order[tid]  = counter + rank;
            s_parent[tid] = par;
            atomicOr(&visw[tid >> 5], 1u << (tid & 31));
        }
        counter += cnt;
        __syncthreads();
        if (cnt == 0) break;
    }

    if (tid < 128) { tnbr[tid][0] = 0; tnbr[tid][1] = 0; tnbr[tid][2] = 0; tnbr[tid][3] = 0; }
    __syncthreads();
    if (tid < 128 && s_order[tid] > 0 && s_order[tid] < INF_) {
        int p = s_parent[tid];
        atomicOr(&tnbr[tid][p >> 5], 1u << (p & 31));
        atomicOr(&tnbr[p][tid >> 5], 1u << (tid & 31));
    }
    __syncthreads();
    if (tid < 128) {
        int d = 1 + __popc(tnbr[tid][0]) + __popc(tnbr[tid][1]) +
                    __popc(tnbr[tid][2]) + __popc(tnbr[tid][3]);
        int num = __popc(actw[0]) + __popc(actw[1]) + __popc(actw[2]) + __popc(actw[3]);
        int act = (actw[tid >> 5] >> (tid & 31)) & 1;
        uint8_t* gbase = wsb + WS_TREE + (size_t)b * 3072;
        *reinterpret_cast<u32x4*>(gbase + tid * 16) =
            *reinterpret_cast<u32x4*>(&tnbr[tid][0]);
        reinterpret_cast<float*>(gbase + 2048)[tid] = 1.0f / (float)d;
        reinterpret_cast<float*>(gbase + 2560)[tid] =
            act ? (1.0f / (float)(num > 0 ? num : 1)) : 0.0f;
    }
}

// ---------------- K2: fused GCN compute per graph (512 threads, chunked pipeline) ----------------
__global__ __launch_bounds__(512, 4) void gcn_kernel(
    const float* __restrict__ x, const uint16_t* __restrict__ ws,
    const uint8_t* __restrict__ wsb,
    const float* __restrict__ b1g, const float* __restrict__ b2g,
    float* __restrict__ wsG)
{
    // region A (32 KB): xa frags -> later M2 half-buffer
    // region B (16 KB): x f32 chunk (swizzled) -> later h1 quarter-chunks
    __shared__ __align__(16) uint16_t xabuf[16384];
    __shared__ __align__(16) uint8_t  rb[16384];
    __shared__ __align__(16) uint32_t tnbr[128][4];
    __shared__ __align__(16) float s_inv[128];
    __shared__ __align__(16) float s_wm[128];

    const int tid  = threadIdx.x;
    const int b    = blockIdx.x;
    const int wid  = tid >> 6;
    const int lane = tid & 63;
    const int l15  = lane & 15;
    const int q    = lane >> 4;

    const float4* xg4 = reinterpret_cast<const float4*>(x + (size_t)b * N_ * D_);

    if (tid < 128) {
        const uint8_t* gbase = wsb + WS_TREE + (size_t)b * 3072;
        u32x4 t4 = *reinterpret_cast<const u32x4*>(gbase + tid * 16);
        tnbr[tid][0] = t4[0]; tnbr[tid][1] = t4[1];
        tnbr[tid][2] = t4[2]; tnbr[tid][3] = t4[3];
        s_inv[tid] = reinterpret_cast<const float*>(gbase + 2048)[tid];
        s_wm[tid]  = reinterpret_cast<const float*>(gbase + 2560)[tid];
    }

    // ---------- agg1: 4 rounds of {stage 32-feat f32 chunk (T14 prefetch) -> gather -> xa frags} ----------
    const int srow0 = tid >> 3;              // 0..63
    const int srow1 = 64 + srow0;
    const int scol  = tid & 7;
    float4 pf0 = xg4[srow0 * 32 + scol];
    float4 pf1 = xg4[srow1 * 32 + scol];

    float4* rbF4 = reinterpret_cast<float4*>(rb);
    const int gv = tid >> 2, gp = tid & 3;   // row, 8-feat part

    for (int r = 0; r < 4; ++r) {
        rbF4[srow0 * 8 + (scol ^ (srow0 & 7))] = pf0;
        rbF4[srow1 * 8 + (scol ^ (srow1 & 7))] = pf1;
        if (r < 3) {                          // prefetch next chunk early (T14)
            pf0 = xg4[srow0 * 32 + (r + 1) * 8 + scol];
            pf1 = xg4[srow1 * 32 + (r + 1) * 8 + scol];
        }
        __syncthreads();
        float acc[8];
        {
            float4 a0 = rbF4[gv * 8 + ((2 * gp + 0) ^ (gv & 7))];
            float4 a1 = rbF4[gv * 8 + ((2 * gp + 1) ^ (gv & 7))];
            acc[0] = a0.x; acc[1] = a0.y; acc[2] = a0.z; acc[3] = a0.w;
            acc[4] = a1.x; acc[5] = a1.y; acc[6] = a1.z; acc[7] = a1.w;
        }
        #pragma unroll
        for (int w = 0; w < 4; ++w) {
            uint32_t m = tnbr[gv][w];
            while (m) {
                int u = (w << 5) + __ffs(m) - 1; m &= m - 1;
                float4 n0 = rbF4[u * 8 + ((2 * gp + 0) ^ (u & 7))];
                float4 n1 = rbF4[u * 8 + ((2 * gp + 1) ^ (u & 7))];
                acc[0] += n0.x; acc[1] += n0.y; acc[2] += n0.z; acc[3] += n0.w;
                acc[4] += n1.x; acc[5] += n1.y; acc[6] += n1.z; acc[7] += n1.w;
            }
        }
        const float inv = s_inv[gv];
        u32x4 wv;
        wv[0] = pack2(acc[0] * inv, acc[1] * inv);
        wv[1] = pack2(acc[2] * inv, acc[3] * inv);
        wv[2] = pack2(acc[4] * inv, acc[5] * inv);
        wv[3] = pack2(acc[6] * inv, acc[7] * inv);
        *reinterpret_cast<u32x4*>(
            &xabuf[(((gv >> 4) * 4 + r) * 64 + gp * 16 + (gv & 15)) * 8]) = wv;
        __syncthreads();
    }

    // ---------- m1/m2 interleaved over 4 h-chunks (64 h each), acc2 persistent ----------
    uint16_t* h1 = reinterpret_cast<uint16_t*>(rb);
    const bf16x8* wsA = reinterpret_cast<const bf16x8*>(ws);
    const bf16x8* wsB = reinterpret_cast<const bf16x8*>(ws + 32768);

    f32x4 acc2[8][2];
    #pragma unroll
    for (int t = 0; t < 8; ++t) {
        acc2[t][0] = (f32x4){0.f, 0.f, 0.f, 0.f};
        acc2[t][1] = (f32x4){0.f, 0.f, 0.f, 0.f};
    }

    const int tml   = wid >> 1;       // 0..3  (h-subtile within chunk)
    const int kbl_w = wid >> 2;       // 0..1  (32-h half within chunk)
    const int tbase = (wid & 1) * 4;  // node-tile group

    for (int hc = 0; hc < 4; ++hc) {
        // m1: C(m=h, n=node) for h-tiles hc*4+tml
        const int tm = hc * 4 + tml;
        f32x4 acc1[4];
        #pragma unroll
        for (int j = 0; j < 4; ++j) acc1[j] = (f32x4){0.f, 0.f, 0.f, 0.f};
        #pragma unroll
        for (int kb = 0; kb < 4; ++kb) {
            bf16x8 afr = wsA[(tm * 4 + kb) * 64 + lane];
            #pragma unroll
            for (int j = 0; j < 4; ++j) {
                bf16x8 bfr = *reinterpret_cast<const bf16x8*>(
                    &xabuf[(((tbase + j) * 4 + kb) * 64 + lane) * 8]);
                acc1[j] = __builtin_amdgcn_mfma_f32_16x16x32_bf16(
                    afr, bfr, acc1[j], 0, 0, 0);
            }
        }
        __syncthreads();   // prev m2 finished reading h1q
        {
            const int m0 = tm * 16 + q * 4;
            f32x4 bb = *reinterpret_cast<const f32x4*>(b1g + m0);
            const int sl = l15 + 16 * (((tml & 1) * 2 + (q >> 1)) & 3);
            #pragma unroll
            for (int j = 0; j < 4; ++j) {
                f32x4 v = acc1[j];
                float v0 = fmaxf(v[0] + bb[0], 0.f), v1 = fmaxf(v[1] + bb[1], 0.f);
                float v2 = fmaxf(v[2] + bb[2], 0.f), v3 = fmaxf(v[3] + bb[3], 0.f);
                u32x2 w; w[0] = pack2(v0, v1); w[1] = pack2(v2, v3);
                *reinterpret_cast<u32x2*>(
                    &h1[(((tbase + j) * 2 + kbl_w) * 64 + sl) * 8 + (q & 1) * 4]) = w;
            }
        }
        __syncthreads();   // h1q ready
        // m2: accumulate this chunk's k-range into persistent acc2
        #pragma unroll
        for (int kbl = 0; kbl < 2; ++kbl) {
            const int kb2 = hc * 2 + kbl;
            bf16x8 bfr0 = wsB[((wid * 2 + 0) * 8 + kb2) * 64 + lane];
            bf16x8 bfr1 = wsB[((wid * 2 + 1) * 8 + kb2) * 64 + lane];
            #pragma unroll
            for (int t = 0; t < 8; ++t) {
                bf16x8 a2 = *reinterpret_cast<const bf16x8*>(
                    &h1[((t * 2 + kbl) * 64 + lane) * 8]);
                acc2[t][0] = __builtin_amdgcn_mfma_f32_16x16x32_bf16(
                    a2, bfr0, acc2[t][0], 0, 0, 0);
                acc2[t][1] = __builtin_amdgcn_mfma_f32_16x16x32_bf16(
                    a2, bfr1, acc2[t][1], 0, 0, 0);
            }
        }
    }

    // ---------- agg2 in two h2-halves via 32 KB M2 half-buffer (region A) ----------
    #pragma unroll
    for (int hf = 0; hf < 2; ++hf) {
        if ((wid >> 2) == hf) {            // owners of this half write M2 frags
            #pragma unroll
            for (int t = 0; t < 8; ++t) {
                const int kbh = t >> 1;
                const int sl  = l15 + 16 * ((2 * t + (q >> 1)) & 3);
                #pragma unroll
                for (int j = 0; j < 2; ++j) {
                    const int tnl = (wid * 2 + j) & 7;
                    f32x4 v = acc2[t][j];
                    u32x2 w; w[0] = pack2(v[0], v[1]); w[1] = pack2(v[2], v[3]);
                    *reinterpret_cast<u32x2*>(
                        &xabuf[((tnl * 4 + kbh) * 64 + sl) * 8 + (q & 1) * 4]) = w;
                }
            }
        }
        __syncthreads();
        f32x4 acc3[8];
        #pragma unroll
        for (int t = 0; t < 8; ++t) acc3[t] = (f32x4){0.f, 0.f, 0.f, 0.f};
        #pragma unroll
        for (int kb = 0; kb < 4; ++kb) {
            bf16x8 bfr = *reinterpret_cast<const bf16x8*>(
                &xabuf[((wid * 4 + kb) * 64 + lane) * 8]);
            #pragma unroll
            for (int t = 0; t < 8; ++t) {
                int v = t * 16 + l15;
                uint32_t word = tnbr[v][kb];
                uint32_t by = (word >> (q * 8)) & 0xFFu;
                if ((v >> 3) == kb * 4 + q) by |= 1u << (v & 7);
                u32x4 pm;
                #pragma unroll
                for (int pp = 0; pp < 4; ++pp)
                    pm[pp] = (((by >> (2 * pp)) & 1u) ? 0x3F80u : 0u) |
                             (((by >> (2 * pp + 1)) & 1u) ? 0x3F800000u : 0u);
                bf16x8 a3 = __builtin_bit_cast(bf16x8, pm);
                acc3[t] = __builtin_amdgcn_mfma_f32_16x16x32_bf16(
                    a3, bfr, acc3[t], 0, 0, 0);
            }
        }
        const int h2 = hf * 128 + wid * 16 + l15;
        const float bc = b2g[h2];
        float ps = 0.f;
        #pragma unroll
        for (int t = 0; t < 8; ++t) {
            const int v0 = t * 16 + q * 4;
            f32x4 iv = *reinterpret_cast<const f32x4*>(&s_inv[v0]);
            f32x4 wm = *reinterpret_cast<const f32x4*>(&s_wm[v0]);
            f32x4 a  = acc3[t];
            #pragma unroll
            for (int r = 0; r < 4; ++r)
                ps += fmaxf(fmaf(a[r], iv[r], bc), 0.f) * wm[r];
        }
        ps += __shfl_xor(ps, 16);
        ps += __shfl_xor(ps, 32);
        if (q == 0) wsG[(size_t)b * 256 + h2] = ps;
        if (hf == 0) __syncthreads();      // protect half-0 reads before half-1 overwrite
    }
}

// ---------------- K3: heads GEMV: out = g @ {Wmu,Wlv} + bias ----------------
__global__ __launch_bounds__(128, 8) void heads_kernel(
    const float* __restrict__ wsG,
    const float* __restrict__ Wmu, const float* __restrict__ bmu,
    const float* __restrict__ Wlv, const float* __restrict__ blv,
    float* __restrict__ out)
{
    __shared__ float sg[256];
    const int tid = threadIdx.x, b = blockIdx.x;
    const float* g = wsG + (size_t)b * 256;
    sg[tid]       = g[tid];
    sg[tid + 128] = g[tid + 128];
    __syncthreads();
    const int which = tid >> 6, l = tid & 63;
    const float* W = which ? Wlv : Wmu;
    float acc = which ? blv[l] : bmu[l];
    #pragma unroll 8
    for (int cc = 0; cc < 256; ++cc)
        acc = fmaf(sg[cc], W[cc * L_ + l], acc);
    out[(size_t)which * B_ * L_ + (size_t)b * L_ + l] = acc;
}

extern "C" void kernel_launch(void* const* d_in, const int* in_sizes, int n_in,
                              void* d_out, int out_size, void* d_ws, size_t ws_size,
                              hipStream_t stream) {
    const float* x   = (const float*)d_in[0];
    const float* adj = (const float*)d_in[1];
    const float* W1  = (const float*)d_in[2];
    const float* b1  = (const float*)d_in[3];
    const float* W2  = (const float*)d_in[4];
    const float* b2  = (const float*)d_in[5];
    const float* Wmu = (const float*)d_in[6];
    const float* bmu = (const float*)d_in[7];
    const float* Wlv = (const float*)d_in[8];
    const float* blv = (const float*)d_in[9];
    float* out = (float*)d_out;
    uint8_t*  wsb = (uint8_t*)d_ws;
    uint16_t* ws  = (uint16_t*)d_ws;
    float*    wsG = (float*)(wsb + WS_G);

    hipLaunchKernelGGL(prep_weights, dim3(48), dim3(256), 0, stream, W1, W2, ws);
    hipLaunchKernelGGL(tree_kernel, dim3(B_), dim3(256), 0, stream, adj, wsb);
    hipLaunchKernelGGL(gcn_kernel, dim3(B_), dim3(512), 0, stream,
                       x, ws, wsb, b1, b2, wsG);
    hipLaunchKernelGGL(heads_kernel, dim3(B_), dim3(128), 0, stream,
                       wsG, Wmu, bmu, Wlv, blv, out);
}